// Round 5
// baseline (667.355 us; speedup 1.0000x reference)
//
#include <hip/hip_runtime.h>

// SparseAutoEncoder: hypernetwork-generated per-sample MLP weights, fused.
// EN layers (rows in en_W2): (2000,200) lin @0, (200,100) tanh @400200, (100,10) lin @420300
// DE layers (rows in de_W2): (10,100) lin @0, (100,200) tanh @1100, (200,2000) lin @21300
// Hyper width K = 64, batch B = 64. h: (b,k) b-major. xT layouts: (i,b) i-major.
//
// R5: O=8 broadcast structure (LDS 48 cyc < VALU 69 cyc per wave-iter per SIMD)
// + EXPLICIT software pipeline: R4's VGPR_Count=132 showed the compiler reused
// w[] regs immediately -> 8 serial load latencies/iter -> VALU 16%. Now w/x are
// double-buffered registers with loads issued one full fma-block before use;
// #pragma unroll 1 keeps the budget at ~210 VGPR (2 waves/SIMD, latency hidden
// in-wave). All layers are i-split partial-sum kernels (atomics into zeroed
// buffers); tanh applied consumer-side during x staging (en3, de3 only).

// ---------------------------------------------------------------------------
// prep: transpose z (64x2000) -> zT (2000x64), and compute h_en, h_de (64x64)
// ---------------------------------------------------------------------------
__global__ __launch_bounds__(256) void prep_kernel(
    const float* __restrict__ z, const float* __restrict__ mu,
    const float* __restrict__ enW0, const float* __restrict__ enb0,
    const float* __restrict__ enW1, const float* __restrict__ enb1,
    const float* __restrict__ deW0, const float* __restrict__ deb0,
    const float* __restrict__ deW1, const float* __restrict__ deb1,
    float* __restrict__ zT, float* __restrict__ hen, float* __restrict__ hde)
{
    __shared__ float tile[64 * 65];
    __shared__ float h0s[4][64];
    const int bid  = blockIdx.x;
    const int lane = threadIdx.x & 63;
    const int g    = threadIdx.x >> 6;

    if (bid < 32) {
        const int t0 = bid * 64;
        for (int bb = g; bb < 64; bb += 4) {
            int i = t0 + lane;
            tile[bb * 65 + lane] = (i < 2000) ? z[bb * 2000 + i] : 0.f;
        }
        __syncthreads();
        for (int ii = g; ii < 64; ii += 4) {
            int i = t0 + ii;
            if (i < 2000) zT[i * 64 + lane] = tile[lane * 65 + ii];
        }
    } else {
        const int task  = (bid - 32) * 4 + g;   // 0..127
        const int which = task >> 6;            // 0 = en, 1 = de
        const int b     = task & 63;
        const float* W0 = which ? deW0 : enW0;
        const float* b0 = which ? deb0 : enb0;
        const float* W1 = which ? deW1 : enW1;
        const float* b1 = which ? deb1 : enb1;
        float* hout     = which ? hde : hen;
        const int j = lane;
        float m0 = mu[b * 4 + 0], m1 = mu[b * 4 + 1], m2 = mu[b * 4 + 2], m3 = mu[b * 4 + 3];
        float v = tanhf(m0 * W0[j * 4 + 0] + m1 * W0[j * 4 + 1] +
                        m2 * W0[j * 4 + 2] + m3 * W0[j * 4 + 3] + b0[j]);
        h0s[g][j] = v;
        __syncthreads();
        float a = b1[j];
        const float* W1r = W1 + j * 64;
        #pragma unroll 8
        for (int k = 0; k < 64; ++k) a = fmaf(h0s[g][k], W1r[k], a);
        hout[b * 64 + j] = tanhf(a);
    }
}

// ---------------------------------------------------------------------------
// pipelined helpers
// ---------------------------------------------------------------------------
template <int O>
__device__ __forceinline__ void fma_block(float (&acc)[O][16], const float4 (&x)[4],
                                          const float (&w)[O]) {
    #pragma unroll
    for (int oo = 0; oo < O; ++oo) {
        const float ww = w[oo];
        #pragma unroll
        for (int q = 0; q < 4; ++q) {
            acc[oo][4 * q + 0] = fmaf(x[q].x, ww, acc[oo][4 * q + 0]);
            acc[oo][4 * q + 1] = fmaf(x[q].y, ww, acc[oo][4 * q + 1]);
            acc[oo][4 * q + 2] = fmaf(x[q].z, ww, acc[oo][4 * q + 2]);
            acc[oo][4 * q + 3] = fmaf(x[q].w, ww, acc[oo][4 * q + 3]);
        }
    }
}

template <int O, int NI>
__device__ __forceinline__ void wload(float (&w)[O], const float* __restrict__ Wb, int i) {
    #pragma unroll
    for (int oo = 0; oo < O; ++oo) w[oo] = Wb[(size_t)oo * NI * 64 + (size_t)i * 64];
}

__device__ __forceinline__ void xload(float4 (&x)[4], const float4* xw, int i) {
    #pragma unroll
    for (int q = 0; q < 4; ++q) x[q] = xw[i * 16 + q];
}

// ---------------------------------------------------------------------------
// O-blocked, software-pipelined fused hyper-FC partial layer:
//   y[o,b] += sum_k (T[o,b,k] + [s==0]*Wbias[o,k]) * h[b,k]
//             + sum_{i in chunk} x[b,i]*b2[o*NI+i] + [s==0]*b2[NO*NI+o]
//   T[o,b,k] = sum_{i in chunk} act(xT[i,b]) * W2[(o*NI+i),k]
// All writes are atomicAdd into zeroed targets. TANHX: tanh on staged x.
// OS1: 64 -> yT[o*64+b]; else yT[b*OS1+o]. OS2>0: also yT2[b*OS2+o].
// ---------------------------------------------------------------------------
template <int NI, int NO, int O, int NSPLIT, bool TANHX, int OS1, int OS2>
__global__ __launch_bounds__(256) void fco2_kernel(
    const float* __restrict__ xT,   // NI x 64 (i-major)
    const float* __restrict__ h,    // 64 x 64 (b-major)
    const float* __restrict__ W2,   // layer base, (NO*NI+NO) x 64
    const float* __restrict__ b2,   // layer base, NO*NI+NO
    float* __restrict__ yT, float* __restrict__ yT2)
{
    constexpr int CH = NI / NSPLIT;          // even for all instantiations
    __shared__ __align__(16) float xs[CH * 64];
    __shared__ float b2s[O][CH];
    __shared__ float xbs[O][64];
    const int lane = threadIdx.x & 63;
    const int wave = threadIdx.x >> 6;
    const int ot = blockIdx.x / NSPLIT;
    const int s  = blockIdx.x - ot * NSPLIT;
    const int o0 = ot * O;
    const int i0 = s * CH;

    // stage x chunk (activated) + O b2 rows into LDS
    {
        const float4* __restrict__ src = (const float4*)(xT + i0 * 64);
        float4* dst = (float4*)xs;
        for (int u = threadIdx.x; u < CH * 16; u += 256) {
            float4 v = src[u];
            if (TANHX) { v.x = tanhf(v.x); v.y = tanhf(v.y); v.z = tanhf(v.z); v.w = tanhf(v.w); }
            dst[u] = v;
        }
        for (int u = threadIdx.x; u < O * CH; u += 256) {
            int oo = u / CH, i = u - oo * CH;
            b2s[oo][i] = b2[(size_t)(o0 + oo) * NI + i0 + i];
        }
    }
    __syncthreads();

    const float* __restrict__ Wb = W2 + ((size_t)o0 * NI + i0) * 64 + lane;
    const float4* xw = (const float4*)(xs + wave * 16);   // stride 16 float4 per i

    float acc[O][16];
    #pragma unroll
    for (int oo = 0; oo < O; ++oo)
        #pragma unroll
        for (int j = 0; j < 16; ++j) acc[oo][j] = 0.f;

    // software-pipelined main loop (manual 2x unroll, double-buffered w/x)
    float w0[O], w1[O];
    float4 xr0[4], xr1[4];
    wload<O, NI>(w0, Wb, 0);
    wload<O, NI>(w1, Wb, 1);
    xload(xr0, xw, 0);
    #pragma unroll 1
    for (int i = 0; i < CH; i += 2) {
        const int ip2 = (i + 2 < CH) ? i + 2 : 0;
        const int ip3 = (i + 3 < CH) ? i + 3 : 0;
        xload(xr1, xw, i + 1);
        fma_block<O>(acc, xr0, w0);
        wload<O, NI>(w0, Wb, ip2);       // in flight across next fma block
        xload(xr0, xw, ip2);
        fma_block<O>(acc, xr1, w1);
        wload<O, NI>(w1, Wb, ip3);
    }

    // bias-dot epilogue: lane = b; wave w covers oo in {w, w+4, ...}
    constexpr int OPW = (O + 3) / 4;
    {
        float xbacc[OPW];
        #pragma unroll
        for (int u = 0; u < OPW; ++u) xbacc[u] = 0.f;
        #pragma unroll 4
        for (int i = 0; i < CH; ++i) {
            float xv = xs[i * 64 + lane];
            #pragma unroll
            for (int u = 0; u < OPW; ++u) {
                int oo = wave + 4 * u;
                if (oo < O) xbacc[u] = fmaf(xv, b2s[oo][i], xbacc[u]);
            }
        }
        #pragma unroll
        for (int u = 0; u < OPW; ++u) {
            int oo = wave + 4 * u;
            if (oo < O) xbs[oo][lane] = xbacc[u];
        }
    }
    __syncthreads();

    // k-contraction with h; butterfly over 64 lanes per (oo, b)
    float wb[O];
    #pragma unroll
    for (int oo = 0; oo < O; ++oo)
        wb[oo] = (s == 0) ? W2[((size_t)NO * NI + o0 + oo) * 64 + lane] : 0.f;

    float myv[O];
    #pragma unroll
    for (int oo = 0; oo < O; ++oo) myv[oo] = 0.f;
    #pragma unroll
    for (int j = 0; j < 16; ++j) {
        int b = wave * 16 + j;
        float hv = h[b * 64 + lane];
        #pragma unroll
        for (int oo = 0; oo < O; ++oo) {
            float v = (acc[oo][j] + wb[oo]) * hv;
            #pragma unroll
            for (int m = 32; m >= 1; m >>= 1) v += __shfl_xor(v, m, 64);
            if (lane == j) myv[oo] = v;
        }
    }
    if (lane < 16) {
        int b = wave * 16 + lane;
        #pragma unroll
        for (int oo = 0; oo < O; ++oo) {
            float outv = myv[oo] + xbs[oo][b];
            if (s == 0) outv += b2[(size_t)NO * NI + o0 + oo];
            if (OS1 == 64) atomicAdd(&yT[(o0 + oo) * 64 + b], outv);
            else           atomicAdd(&yT[(size_t)b * OS1 + o0 + oo], outv);
            if (OS2 > 0)   atomicAdd(&yT2[(size_t)b * OS2 + o0 + oo], outv);
        }
    }
}

extern "C" void kernel_launch(void* const* d_in, const int* in_sizes, int n_in,
                              void* d_out, int out_size, void* d_ws, size_t ws_size,
                              hipStream_t stream)
{
    const float* z    = (const float*)d_in[0];
    const float* mu   = (const float*)d_in[1];
    const float* enW0 = (const float*)d_in[2];
    const float* enb0 = (const float*)d_in[3];
    const float* enW1 = (const float*)d_in[4];
    const float* enb1 = (const float*)d_in[5];
    const float* enW2 = (const float*)d_in[6];
    const float* enb2 = (const float*)d_in[7];
    const float* deW0 = (const float*)d_in[8];
    const float* deb0 = (const float*)d_in[9];
    const float* deW1 = (const float*)d_in[10];
    const float* deb1 = (const float*)d_in[11];
    const float* deW2 = (const float*)d_in[12];
    const float* deb2 = (const float*)d_in[13];

    float* ws  = (float*)d_ws;
    float* zT  = ws;                 // 2000*64
    float* hen = zT + 128000;        // 64*64
    float* hde = hen + 4096;         // 64*64
    // contiguous zeroed region: y1,y2,y3,d1,d2
    float* y1  = hde + 4096;         // 200*64
    float* y2  = y1 + 200 * 64;      // 100*64
    float* y3  = y2 + 100 * 64;      // 10*64   (x_enc, o-major)
    float* d1  = y3 + 10 * 64;       // 100*64
    float* d2  = d1 + 100 * 64;      // 200*64
    float* out = (float*)d_out;

    hipMemsetAsync(y1, 0, (size_t)(200 + 100 + 10 + 100 + 200) * 64 * sizeof(float), stream);
    hipMemsetAsync(out, 0, (size_t)128640 * sizeof(float), stream);
    prep_kernel<<<64, 256, 0, stream>>>(z, mu, enW0, enb0, enW1, enb1,
                                        deW0, deb0, deW1, deb1, zT, hen, hde);
    // encoder: (2000->200 lin), (200->100, out consumed w/ tanh), (100->10 lin)
    fco2_kernel<2000, 200, 8, 25, false, 64, 0><<<625, 256, 0, stream>>>(zT, hen, enW2, enb2, y1, nullptr);
    fco2_kernel< 200, 100, 4,  4, false, 64, 0><<<100, 256, 0, stream>>>(y1, hen, enW2 + (size_t)400200 * 64, enb2 + 400200, y2, nullptr);
    fco2_kernel< 100,  10, 2,  2, true,  64, 10><<< 10, 256, 0, stream>>>(y2, hen, enW2 + (size_t)420300 * 64, enb2 + 420300, y3, out + 128000);
    // decoder: (10->100 lin), (100->200, consumed w/ tanh), (200->2000 lin -> d_out direct)
    fco2_kernel<  10, 100, 4,  1, false, 64, 0><<< 25, 256, 0, stream>>>(y3, hde, deW2, deb2, d1, nullptr);
    fco2_kernel< 100, 200, 4,  2, false, 64, 0><<<100, 256, 0, stream>>>(d1, hde, deW2 + (size_t)1100 * 64, deb2 + 1100, d2, nullptr);
    fco2_kernel< 200, 2000, 8, 4, true, 2000, 0><<<1000, 256, 0, stream>>>(d2, hde, deW2 + (size_t)21300 * 64, deb2 + 21300, out, nullptr);
}